// Round 7
// baseline (1009.707 us; speedup 1.0000x reference)
//
#include <hip/hip_runtime.h>
#include <math.h>

// Problem constants
#define B_  256
#define T_  32
#define S_  128
#define I_  256
#define H_  1024
#define O_  256
#define G4  4096   // 4*H
#define K2  2048   // 2*H

typedef __attribute__((ext_vector_type(8))) short bf16x8;
typedef __attribute__((ext_vector_type(4))) float f32x4;

#define MFMA16(a, b, c) __builtin_amdgcn_mfma_f32_16x16x32_bf16(a, b, c, 0, 0, 0)

__device__ __forceinline__ unsigned short f2bf(float f) {
    unsigned int u = __float_as_uint(f);
    u = (u + 0x7FFFu + ((u >> 16) & 1u)) >> 16;
    return (unsigned short)u;
}
__device__ __forceinline__ float sigm(float x) { return 1.0f / (1.0f + __expf(-x)); }

// system-coherent 16B load: bypasses L1+L2, reads the memside (MALL/L3).
__device__ __forceinline__ bf16x8 ldg_sys(const unsigned short* p) {
    bf16x8 r;
    asm volatile("global_load_dwordx4 %0, %1, off sc0 sc1"
                 : "=v"(r) : "v"(p) : "memory");
    return r;
}
// system-coherent 2B store: writes through to the memside.
__device__ __forceinline__ void stg_sys16(unsigned short* p, unsigned short v) {
    asm volatile("global_store_short %0, %1, off sc0 sc1"
                 :: "v"(p), "v"(v) : "memory");
}
// flag ops: memside-coherent dword access; load waits internally so the
// returned value is genuinely ready (rule #18: compiler can't see the load).
__device__ __forceinline__ unsigned ldg_flag(const unsigned* p) {
    unsigned r;
    asm volatile("global_load_dword %0, %1, off sc0 sc1\n\ts_waitcnt vmcnt(0)"
                 : "=v"(r) : "v"(p) : "memory");
    return r;
}
__device__ __forceinline__ void stg_flag(unsigned* p, unsigned v) {
    asm volatile("global_store_dword %0, %1, off sc0 sc1"
                 :: "v"(p), "v"(v) : "memory");
}

// ---------------------------------------------------------------------------
// prep: bf16-convert + gate-reorder weights, convert x (zero t=0), convert
// enc -> encB bf16, zero h0/h1.  Gate reorder: row r -> n = 4*(r%H)+(r/H).
// Also zeroes the 256-entry flag array.
// ---------------------------------------------------------------------------
__global__ void prep_kernel(
    const float* __restrict__ x, const float* __restrict__ enc,
    const float* __restrict__ Wih, const float* __restrict__ Whh,
    const float* __restrict__ bih, const float* __restrict__ bhh,
    const float* __restrict__ Wfc,
    unsigned short* __restrict__ WihR, unsigned short* __restrict__ WhhR,
    unsigned short* __restrict__ WfcR, float* __restrict__ biasR,
    unsigned short* __restrict__ xs, unsigned short* __restrict__ encB,
    unsigned short* __restrict__ h0, unsigned short* __restrict__ h1,
    unsigned* __restrict__ bar)
{
    if (blockIdx.x == 0 && threadIdx.x < 256) bar[threadIdx.x] = 0u;

    const long NWHH = (long)G4 * H_;      // 4,194,304
    const long NWIH = (long)G4 * I_;      // 1,048,576
    const long NWFC = (long)O_ * K2;      //   524,288
    const long NB   = G4;
    const long NX   = (long)B_ * T_ * I_; // 2,097,152
    const long NE   = (long)B_ * S_ * H_; // 33,554,432
    const long NH   = (long)B_ * H_;      //   262,144
    const long total = NWHH + NWIH + NWFC + NB + NX + NE + 2 * NH;
    for (long i = (long)blockIdx.x * blockDim.x + threadIdx.x; i < total;
         i += (long)gridDim.x * blockDim.x) {
        long j = i;
        if (j < NE) { encB[j] = f2bf(enc[j]); continue; }
        j -= NE;
        if (j < NWHH) {
            int r = (int)(j >> 10), k = (int)(j & 1023);
            int n = ((r & 1023) << 2) | (r >> 10);
            WhhR[(long)n * H_ + k] = f2bf(Whh[j]);
            continue;
        }
        j -= NWHH;
        if (j < NWIH) {
            int r = (int)(j >> 8), k = (int)(j & 255);
            int n = ((r & 1023) << 2) | (r >> 10);
            WihR[(long)n * I_ + k] = f2bf(Wih[j]);
            continue;
        }
        j -= NWIH;
        if (j < NWFC) { WfcR[j] = f2bf(Wfc[j]); continue; }
        j -= NWFC;
        if (j < NB) {
            int r = (int)j;
            int n = ((r & 1023) << 2) | (r >> 10);
            biasR[n] = bih[r] + bhh[r];
            continue;
        }
        j -= NB;
        if (j < NX) {
            int t = (int)((j >> 8) & 31);
            xs[j] = (t == 0) ? (unsigned short)0 : f2bf(x[j]);
            continue;
        }
        j -= NX;
        if (j < NH) { h0[j] = 0; continue; }
        j -= NH;
        h1[j] = 0;
    }
}

// ---------------------------------------------------------------------------
// steps: ALL 32 LSTM steps in ONE persistent cooperative kernel.
// grid 256 blocks x 512 threads (8 waves, 2/SIMD), 1 block/CU.
// Block tile 64m x 64n; wave tile 32m x 16n. Whh slab (128 KiB) in LDS
// (XOR-swizzled), Wih in registers, c register-resident.
// h exchange through the MEMSIDE coherence point (sc0 sc1) -- no fences.
// FLAG-ARRAY barrier (r6's single atomicAdd counter = 256 serialized
// same-line RMWs/step ~ 15us/step convoy):
//   - flags[mt*64 + xcd*8 + nt], one dword per block, NO atomics.
//   - arrive: vmcnt(0) h-stores -> syncthreads -> tid0 plain sc0sc1 store t+1.
//   - wait: wave0 lanes each poll ONE flag of their m-group (64 blocks),
//     lane-divergent until all >= t; then syncthreads.
// Dependency groups of 64 (same mt) decouple the 4 step-chains.
// ---------------------------------------------------------------------------
__global__ __launch_bounds__(512, 2) void steps_kernel(
    const unsigned short* __restrict__ xs,   // [B][T][I] bf16
    const unsigned short* __restrict__ WihR, // [4H][I]
    const unsigned short* __restrict__ WhhR, // [4H][H]
    const float* __restrict__ biasR,         // [4H]
    unsigned short* __restrict__ h0b,        // [B][H] bf16 (zeroed)
    unsigned short* __restrict__ h1b,        // [B][H] bf16 (zeroed)
    unsigned short* __restrict__ hall,       // [B][T][H] bf16
    unsigned* __restrict__ bar)              // flags[256] (zeroed)
{
    __shared__ unsigned short Wlds[64 * 1024];  // 128 KiB weight slab
    __shared__ float Gs[64 * 68];               // 17408 B gates

    const int tid = threadIdx.x;
    const int lane = tid & 63, wave = tid >> 6;
    const int quad = lane >> 4, l16 = lane & 15;
    const int wm = wave >> 2, wn = wave & 3;

    // XCD-aware persistent mapping: 8 n-tiles x 4 m-tiles per XCD
    const int id = blockIdx.x;
    const int xcd = id & 7, slot = id >> 3;   // slot 0..31
    const int nt = slot >> 2, mt = slot & 3;
    const int n0 = (xcd * 8 + nt) * 64;
    const int m0 = mt * 64;

    // barrier addressing: group = mt (the 64 blocks producing rows m0..m0+63)
    unsigned* myflag = bar + mt * 64 + xcd * 8 + nt;
    const unsigned* gflags = bar + mt * 64;

    // ---- one-time: stage Whh slab rows [n0, n0+64) into LDS (swizzled) ----
    for (int i = 0; i < 16; i++) {
        int q = i * 512 + tid;                // 8192 16B-chunks
        int row = q >> 7, kc = q & 127;       // 128 chunks per row
        int e = kc * 8;
        int de = row * 1024 + (e ^ ((row & 7) << 3));
        *(uint4*)(Wlds + de) = *(const uint4*)(WhhR + (long)(n0 + row) * H_ + e);
    }

    // Wih fragments in registers (16 n-rows x 256 k per wave = 32 VGPRs)
    const int nw = n0 + wn * 16 + l16;        // this lane's weight/gate col
    bf16x8 bwx[8];
    {
        const unsigned short* px = WihR + (long)nw * I_ + quad * 8;
#pragma unroll
        for (int kk = 0; kk < 8; kk++) bwx[kk] = *(const bf16x8*)(px + kk * 32);
    }
    const float bj = biasR[nw];

    // B ds_read base for this lane
    const unsigned short* bbase = Wlds + (wn * 16 + l16) * 1024;
    const int swz = (l16 & 7) << 3;

    // A row bases (2 m-fragments of 16 rows each)
    const unsigned short* xrow[2];
    long hoff[2];
#pragma unroll
    for (int i = 0; i < 2; i++) {
        int ar = m0 + wm * 32 + i * 16 + l16;
        xrow[i] = xs + (long)ar * T_ * I_ + quad * 8;
        hoff[i] = (long)ar * H_ + quad * 8;
    }

    // register-resident c: thread handles items p = j*512 + tid
    float c_reg[2] = {0.f, 0.f};

    __syncthreads();  // Wlds staged

#pragma unroll 1
    for (int t = 0; t < T_; t++) {
        const unsigned short* hp = (t & 1) ? h1b : h0b;
        unsigned short* hn = (t & 1) ? h0b : h1b;

        const f32x4 z = {0.f, 0.f, 0.f, 0.f};
        f32x4 acc[2] = {z, z};

        // phase 1: x_t @ Wih^T (K = 256) — independent of h; overlaps barrier
        {
            bf16x8 a[8][2];
#pragma unroll
            for (int kk = 0; kk < 8; kk++)
#pragma unroll
                for (int i = 0; i < 2; i++)
                    a[kk][i] = *(const bf16x8*)(xrow[i] + (long)t * I_ + kk * 32);
#pragma unroll
            for (int kk = 0; kk < 8; kk++)
#pragma unroll
                for (int i = 0; i < 2; i++)
                    acc[i] = MFMA16(a[kk][i], bwx[kk], acc[i]);
        }

        // wait: all 64 same-mt blocks published h_{t-1} (flag >= t)
        if (t > 0) {
            if (tid < 64) {
                int spins = 0;
                while (ldg_flag(gflags + tid) < (unsigned)t &&
                       spins < (1 << 20)) {
                    __builtin_amdgcn_s_sleep(1);
                    ++spins;
                }
            }
            __syncthreads();
            __builtin_amdgcn_sched_barrier(0);
        }

        // phase 2: h_prev @ Whh^T (K = 1024) — 4 chunks; A memside, B LDS
#pragma unroll
        for (int kc = 0; kc < 4; kc++) {
            bf16x8 a[8][2];
#pragma unroll
            for (int kk = 0; kk < 8; kk++)
#pragma unroll
                for (int i = 0; i < 2; i++)
                    a[kk][i] = ldg_sys(hp + hoff[i] + (long)(kc * 8 + kk) * 32);
            bf16x8 bb[8];
#pragma unroll
            for (int kk = 0; kk < 8; kk++) {
                int e = ((kc * 8 + kk) * 32 + quad * 8) ^ swz;
                bb[kk] = *(const bf16x8*)(bbase + e);
            }
            asm volatile("s_waitcnt vmcnt(0)" ::: "memory");
            __builtin_amdgcn_sched_barrier(0);
#pragma unroll
            for (int kk = 0; kk < 8; kk++)
#pragma unroll
                for (int i = 0; i < 2; i++)
                    acc[i] = MFMA16(a[kk][i], bb[kk], acc[i]);
        }

        // gates + bias -> LDS (row = wm*32 + i*16 + quad*4 + r, col = wn*16+l16)
#pragma unroll
        for (int i = 0; i < 2; i++)
#pragma unroll
            for (int r = 0; r < 4; r++)
                Gs[(wm * 32 + i * 16 + quad * 4 + r) * 68 + wn * 16 + l16] =
                    acc[i][r] + bj;
        __syncthreads();

        // fused cell: 64 rows x 16 units; c register-resident
#pragma unroll
        for (int j = 0; j < 2; j++) {
            int p = j * 512 + tid;
            int row = p >> 4, u = p & 15;
            float gi = Gs[row * 68 + u * 4 + 0];
            float gf = Gs[row * 68 + u * 4 + 1];
            float gg = Gs[row * 68 + u * 4 + 2];
            float go = Gs[row * 68 + u * 4 + 3];
            int b = m0 + row;
            int jg = (n0 >> 2) + u;
            float ii = sigm(gi), ff = sigm(gf), g3 = tanhf(gg), oo = sigm(go);
            float cn = ff * c_reg[j] + ii * g3;
            float hh = oo * tanhf(cn);
            c_reg[j] = cn;
            unsigned short hb = f2bf(hh);
            stg_sys16(hn + (long)b * H_ + jg, hb);     // memside-coherent
            hall[((long)b * T_ + t) * H_ + jg] = hb;   // normal (read post-kernel)
        }

        // arrive: h stores acked at coherence point, then set own flag
        if (t < T_ - 1) {
            asm volatile("s_waitcnt vmcnt(0)" ::: "memory");
            __syncthreads();   // all waves drained; also protects Gs
            if (tid == 0) stg_flag(myflag, (unsigned)(t + 1));
        }
    }
}

// ---------------------------------------------------------------------------
// scores: per-b S = hall[b](32x1024) @ encB[b]^T (128x1024)^T, fused softmax.
// ---------------------------------------------------------------------------
__global__ __launch_bounds__(256) void scores_kernel(
    const unsigned short* __restrict__ hall, // [B][T][H]
    const unsigned short* __restrict__ encB, // [B][S][H]
    float* __restrict__ probs,               // [B][T][S]
    unsigned short* __restrict__ PB)         // [B][T][S] bf16
{
    __shared__ float Sc[32 * 132];

    const int tid = threadIdx.x;
    const int lane = tid & 63, wave = tid >> 6;
    const int quad = lane >> 4, l16 = lane & 15;
    const int b = blockIdx.x;
    const int nw = wave;  // 4 waves x 32 s-cols

    const unsigned short* pa0 = hall + ((long)b * T_ + l16) * H_ + quad * 8;
    const unsigned short* pa1 = hall + ((long)b * T_ + 16 + l16) * H_ + quad * 8;
    const unsigned short* pb0 = encB + ((long)b * S_ + nw * 32 + l16) * H_ + quad * 8;
    const unsigned short* pb1 = pb0 + 16 * H_;

    const f32x4 z = {0.f, 0.f, 0.f, 0.f};
    f32x4 acc00 = z, acc01 = z, acc10 = z, acc11 = z;

#pragma unroll 4
    for (int k0 = 0; k0 < H_; k0 += 32) {
        bf16x8 a0 = *(const bf16x8*)(pa0 + k0);
        bf16x8 a1 = *(const bf16x8*)(pa1 + k0);
        bf16x8 b0 = *(const bf16x8*)(pb0 + k0);
        bf16x8 b1 = *(const bf16x8*)(pb1 + k0);
        acc00 = MFMA16(a0, b0, acc00);
        acc01 = MFMA16(a0, b1, acc01);
        acc10 = MFMA16(a1, b0, acc10);
        acc11 = MFMA16(a1, b1, acc11);
    }
#pragma unroll
    for (int r = 0; r < 4; r++) {
        int row0 = quad * 4 + r;
        int col0 = nw * 32 + l16;
        Sc[row0 * 132 + col0]            = acc00[r];
        Sc[row0 * 132 + col0 + 16]       = acc01[r];
        Sc[(row0 + 16) * 132 + col0]      = acc10[r];
        Sc[(row0 + 16) * 132 + col0 + 16] = acc11[r];
    }
    __syncthreads();
    // softmax: wave handles 8 rows; 128 cols = 2 per lane
    for (int r = 0; r < 8; r++) {
        int row = wave * 8 + r;
        float v0 = Sc[row * 132 + lane];
        float v1 = Sc[row * 132 + 64 + lane];
        float mx = fmaxf(v0, v1);
#pragma unroll
        for (int off = 32; off > 0; off >>= 1) mx = fmaxf(mx, __shfl_xor(mx, off));
        float e0 = __expf(v0 - mx), e1 = __expf(v1 - mx);
        float s = e0 + e1;
#pragma unroll
        for (int off = 32; off > 0; off >>= 1) s += __shfl_xor(s, off);
        float inv = 1.0f / s;
        float p0 = e0 * inv, p1 = e1 * inv;
        long o = ((long)b * T_ + row) * S_;
        probs[o + lane] = p0;
        probs[o + 64 + lane] = p1;
        PB[o + lane] = f2bf(p0);
        PB[o + 64 + lane] = f2bf(p1);
    }
}

// ---------------------------------------------------------------------------
// ctx: C[b] = P[b](32x128) @ encB[b](128x1024) -> CTX bf16. grid(B, 4).
// ---------------------------------------------------------------------------
__global__ __launch_bounds__(256) void ctx_kernel(
    const unsigned short* __restrict__ encB, // [B][S][H]
    const unsigned short* __restrict__ PB,   // [B][T][S]
    unsigned short* __restrict__ ctxo)       // [B*T][H] bf16
{
    __shared__ unsigned short Es[S_ * 256];  // 64 KB

    const int tid = threadIdx.x;
    const int lane = tid & 63, wave = tid >> 6;
    const int quad = lane >> 4, l16 = lane & 15;
    const int b = blockIdx.x;
    const int h0 = blockIdx.y * 256;

    // stage encB[b][:, h0:h0+256] -> LDS [s][256]
    for (int i = tid; i < S_ * 32; i += 256) {
        int s = i >> 5, hc = (i & 31) * 8;
        *(uint4*)(Es + s * 256 + hc) =
            *(const uint4*)(encB + ((long)b * S_ + s) * H_ + h0 + hc);
    }
    // A fragments (P rows t, k = s), direct loads
    bf16x8 a[2][4];
#pragma unroll
    for (int i = 0; i < 2; i++)
#pragma unroll
        for (int ks = 0; ks < 4; ks++)
            a[i][ks] = *(const bf16x8*)(PB + ((long)b * T_ + i * 16 + l16) * S_ +
                                        ks * 32 + quad * 8);
    __syncthreads();

    f32x4 acc[2][4];
    const f32x4 z = {0.f, 0.f, 0.f, 0.f};
#pragma unroll
    for (int i = 0; i < 2; i++)
#pragma unroll
        for (int j = 0; j < 4; j++) acc[i][j] = z;

    const int cw = wave * 64;
#pragma unroll
    for (int ks = 0; ks < 4; ks++) {
        const int kb = ks * 32 + quad * 8;
#pragma unroll
        for (int j = 0; j < 4; j++) {
            const int col = cw + j * 16 + l16;
            bf16x8 bb;
#pragma unroll
            for (int e = 0; e < 8; e++) bb[e] = (short)Es[(kb + e) * 256 + col];
            acc[0][j] = MFMA16(a[0][ks], bb, acc[0][j]);
            acc[1][j] = MFMA16(a[1][ks], bb, acc[1][j]);
        }
    }
#pragma unroll
    for (int i = 0; i < 2; i++)
#pragma unroll
        for (int j = 0; j < 4; j++)
#pragma unroll
            for (int r = 0; r < 4; r++) {
                int row = i * 16 + quad * 4 + r;
                int col = h0 + cw + j * 16 + l16;
                ctxo[((long)b * T_ + row) * H_ + col] = f2bf(acc[i][j][r]);
            }
}

// ---------------------------------------------------------------------------
// fc: out = [ctx | h](8192x2048) @ WfcR^T (256x2048) + bfc. Tile 64x128.
// ---------------------------------------------------------------------------
__global__ __launch_bounds__(256) void fc_kernel(
    const unsigned short* __restrict__ ctxo, // [B*T][H]
    const unsigned short* __restrict__ hall, // [B*T][H]
    const unsigned short* __restrict__ WfcR,
    const float* __restrict__ bfc,
    float* __restrict__ out)
{
    __shared__ __align__(16) unsigned short As[64 * 40];
    __shared__ __align__(16) unsigned short Bs[128 * 40];

    const int tid = threadIdx.x;
    const int lane = tid & 63, wave = tid >> 6;
    const int wm = wave >> 1, wn = wave & 1;
    const int quad = lane >> 4, l16 = lane & 15;
    const int n0 = blockIdx.x * 128, m0 = blockIdx.y * 64;

    const int arow = tid >> 2, akc = (tid & 3) * 8;
    const int brow = tid >> 1, bkc = (tid & 1) * 16;

    f32x4 acc[2][4];
    const f32x4 z = {0.f, 0.f, 0.f, 0.f};
#pragma unroll
    for (int i = 0; i < 2; i++)
#pragma unroll
        for (int j = 0; j < 4; j++) acc[i][j] = z;

    for (int k0 = 0; k0 < K2; k0 += 32) {
        const unsigned short* asrc = (k0 < H_)
            ? ctxo + (long)(m0 + arow) * H_ + k0 + akc
            : hall + (long)(m0 + arow) * H_ + (k0 - H_) + akc;
        *(uint4*)(As + arow * 40 + akc) = *(const uint4*)asrc;
        const unsigned short* src = WfcR + (long)(n0 + brow) * K2 + k0 + bkc;
        *(uint4*)(Bs + brow * 40 + bkc)     = *(const uint4*)src;
        *(uint4*)(Bs + brow * 40 + bkc + 8) = *(const uint4*)(src + 8);
        __syncthreads();
        bf16x8 a0 = *(const bf16x8*)(As + (wm * 32 + l16) * 40 + quad * 8);
        bf16x8 a1 = *(const bf16x8*)(As + (wm * 32 + 16 + l16) * 40 + quad * 8);
#pragma unroll
        for (int j = 0; j < 4; j++) {
            bf16x8 bb = *(const bf16x8*)(Bs + (wn * 64 + j * 16 + l16) * 40 + quad * 8);
            acc[0][j] = MFMA16(a0, bb, acc[0][j]);
            acc[1][j] = MFMA16(a1, bb, acc[1][j]);
        }
        __syncthreads();
    }
#pragma unroll
    for (int i = 0; i < 2; i++)
#pragma unroll
        for (int j = 0; j < 4; j++)
#pragma unroll
            for (int r = 0; r < 4; r++) {
                int row = m0 + wm * 32 + i * 16 + quad * 4 + r;
                int col = n0 + wn * 64 + j * 16 + l16;
                out[(long)row * O_ + col] = acc[i][j][r] + bfc[col];
            }
}

// ---------------------------------------------------------------------------
extern "C" void kernel_launch(void* const* d_in, const int* in_sizes, int n_in,
                              void* d_out, int out_size, void* d_ws, size_t ws_size,
                              hipStream_t stream) {
    const float* x   = (const float*)d_in[0];
    const float* enc = (const float*)d_in[1];
    const float* Wih = (const float*)d_in[2];
    const float* Whh = (const float*)d_in[3];
    const float* bih = (const float*)d_in[4];
    const float* bhh = (const float*)d_in[5];
    const float* Wfc = (const float*)d_in[6];
    const float* bfc = (const float*)d_in[7];
    float* out = (float*)d_out;

    char* ws = (char*)d_ws;
    // workspace layout (bytes); total ~120.6 MB
    unsigned short* WIHR = (unsigned short*)(ws + 0);           //  2,097,152
    unsigned short* WHHR = (unsigned short*)(ws + 2097152);     //  8,388,608
    unsigned short* WFCR = (unsigned short*)(ws + 10485760);    //  1,048,576
    float*          BIAS = (float*)         (ws + 11534336);    //     16,384
    unsigned short* XS   = (unsigned short*)(ws + 11550720);    //  4,194,304
    unsigned short* H0   = (unsigned short*)(ws + 15745024);    //    524,288
    unsigned short* H1   = (unsigned short*)(ws + 16269312);    //    524,288
    unsigned*       BAR  = (unsigned*)      (ws + 16793600);    // flags[256]
    unsigned short* HALL = (unsigned short*)(ws + 17842176);    // 16,777,216
    unsigned short* ENCB = (unsigned short*)(ws + 34619392);    // 67,108,864
    unsigned short* PB   = (unsigned short*)(ws + 101728256);   //  2,097,152
    unsigned short* CTX  = (unsigned short*)(ws + 103825408);   // 16,777,216

    prep_kernel<<<8192, 256, 0, stream>>>(x, enc, Wih, Whh, bih, bhh, Wfc,
                                          WIHR, WHHR, WFCR, BIAS, XS, ENCB,
                                          H0, H1, BAR);

    // all 32 LSTM steps in one persistent cooperative launch (512 threads)
    {
        void* args[] = {(void*)&XS, (void*)&WIHR, (void*)&WHHR, (void*)&BIAS,
                        (void*)&H0, (void*)&H1, (void*)&HALL, (void*)&BAR};
        hipLaunchCooperativeKernel(reinterpret_cast<void*>(steps_kernel),
                                   dim3(256), dim3(512), args, 0, stream);
    }

    scores_kernel<<<B_, 256, 0, stream>>>(HALL, ENCB,
                                          out + (long)B_ * T_ * O_, PB);
    ctx_kernel<<<dim3(B_, 4), 256, 0, stream>>>(ENCB, PB, CTX);
    fc_kernel<<<dim3(2, 128), 256, 0, stream>>>(CTX, HALL, WFCR, bfc, out);
}

// Round 10
// 998.526 us; speedup vs baseline: 1.0112x; 1.0112x over previous
//
#include <hip/hip_runtime.h>
#include <math.h>

// Problem constants
#define B_  256
#define T_  32
#define S_  128
#define I_  256
#define H_  1024
#define O_  256
#define G4  4096   // 4*H
#define K2  2048   // 2*H

typedef __attribute__((ext_vector_type(8))) short bf16x8;
typedef __attribute__((ext_vector_type(4))) float f32x4;
typedef __attribute__((ext_vector_type(4))) unsigned u32x4;

#define MFMA16(a, b, c) __builtin_amdgcn_mfma_f32_16x16x32_bf16(a, b, c, 0, 0, 0)

__device__ __forceinline__ unsigned short f2bf(float f) {
    unsigned int u = __float_as_uint(f);
    u = (u + 0x7FFFu + ((u >> 16) & 1u)) >> 16;
    return (unsigned short)u;
}
__device__ __forceinline__ float sigm(float x) { return 1.0f / (1.0f + __expf(-x)); }

// memside-coherent 16B store (write-through; no L2 allocation).
// NOTE: operand must be an ext_vector_type — struct types (uint4) hit
// "indirect register inputs" asm-constraint error on gfx950 (r9 lesson).
__device__ __forceinline__ void stg_sys128(unsigned short* p, u32x4 v) {
    asm volatile("global_store_dwordx4 %0, %1, off sc0 sc1"
                 :: "v"(p), "v"(v) : "memory");
}
// flag ops: memside-coherent dword access; load waits internally.
__device__ __forceinline__ unsigned ldg_flag(const unsigned* p) {
    unsigned r;
    asm volatile("global_load_dword %0, %1, off sc0 sc1\n\ts_waitcnt vmcnt(0)"
                 : "=v"(r) : "v"(p) : "memory");
    return r;
}
__device__ __forceinline__ void stg_flag(unsigned* p, unsigned v) {
    asm volatile("global_store_dword %0, %1, off sc0 sc1"
                 :: "v"(p), "v"(v) : "memory");
}

// ---------------------------------------------------------------------------
// prep: bf16-convert + gate-reorder weights, convert x (zero t=0), convert
// enc -> encB bf16, zero h0.  Gate reorder: row r -> n = 4*(r%H)+(r/H).
// Also zeroes the 256-entry flag array.
// ---------------------------------------------------------------------------
__global__ void prep_kernel(
    const float* __restrict__ x, const float* __restrict__ enc,
    const float* __restrict__ Wih, const float* __restrict__ Whh,
    const float* __restrict__ bih, const float* __restrict__ bhh,
    const float* __restrict__ Wfc,
    unsigned short* __restrict__ WihR, unsigned short* __restrict__ WhhR,
    unsigned short* __restrict__ WfcR, float* __restrict__ biasR,
    unsigned short* __restrict__ xs, unsigned short* __restrict__ encB,
    unsigned short* __restrict__ h0,
    unsigned* __restrict__ bar)
{
    if (blockIdx.x == 0 && threadIdx.x < 256) bar[threadIdx.x] = 0u;

    const long NWHH = (long)G4 * H_;      // 4,194,304
    const long NWIH = (long)G4 * I_;      // 1,048,576
    const long NWFC = (long)O_ * K2;      //   524,288
    const long NB   = G4;
    const long NX   = (long)B_ * T_ * I_; // 2,097,152
    const long NE   = (long)B_ * S_ * H_; // 33,554,432
    const long NH   = (long)B_ * H_;      //   262,144
    const long total = NWHH + NWIH + NWFC + NB + NX + NE + NH;
    for (long i = (long)blockIdx.x * blockDim.x + threadIdx.x; i < total;
         i += (long)gridDim.x * blockDim.x) {
        long j = i;
        if (j < NE) { encB[j] = f2bf(enc[j]); continue; }
        j -= NE;
        if (j < NWHH) {
            int r = (int)(j >> 10), k = (int)(j & 1023);
            int n = ((r & 1023) << 2) | (r >> 10);
            WhhR[(long)n * H_ + k] = f2bf(Whh[j]);
            continue;
        }
        j -= NWHH;
        if (j < NWIH) {
            int r = (int)(j >> 8), k = (int)(j & 255);
            int n = ((r & 1023) << 2) | (r >> 10);
            WihR[(long)n * I_ + k] = f2bf(Wih[j]);
            continue;
        }
        j -= NWIH;
        if (j < NWFC) { WfcR[j] = f2bf(Wfc[j]); continue; }
        j -= NWFC;
        if (j < NB) {
            int r = (int)j;
            int n = ((r & 1023) << 2) | (r >> 10);
            biasR[n] = bih[r] + bhh[r];
            continue;
        }
        j -= NB;
        if (j < NX) {
            int t = (int)((j >> 8) & 31);
            xs[j] = (t == 0) ? (unsigned short)0 : f2bf(x[j]);
            continue;
        }
        j -= NX;
        h0[j] = 0;
    }
}

// ---------------------------------------------------------------------------
// steps: ALL 32 LSTM steps in ONE persistent cooperative kernel.
// grid 256 blocks x 512 threads (8 waves, 2/SIMD), 1 block/CU.
// Block tile 64m x 64n; wave tile 32m x 16n. Whh slab (128 KiB) in LDS
// (XOR-swizzled), Wih in registers, c register-resident.
// h EXCHANGE VIA ADDRESS ROTATION: h_t written ONCE to hall[b][t][:] with
// sc0 sc1 write-through (16B stores gathered via LDS; memside authoritative,
// no L2 allocation). h_{t-1} read with NORMAL CACHED loads: the address is
// fresh each step (2KB-aligned rows; first read per XCD is a compulsory
// L2 miss -> memside -> fresh; 7 same-mt blocks/XCD then hit L2). This cuts
// memside reads 32MB -> 4MB/step vs r7's sc0sc1-everywhere (64x uncached
// amplification), and lets the compiler pipeline the loads (no asm, 2-deep
// static double-buffer, counted vmcnt emitted by compiler).
// Flag-array barrier unchanged (proven r7).
// ---------------------------------------------------------------------------
__global__ __launch_bounds__(512, 2) void steps_kernel(
    const unsigned short* __restrict__ xs,   // [B][T][I] bf16
    const unsigned short* __restrict__ WihR, // [4H][I]
    const unsigned short* __restrict__ WhhR, // [4H][H]
    const float* __restrict__ biasR,         // [4H]
    const unsigned short* __restrict__ h0b,  // [B][H] bf16 (zeroed)
    unsigned short* __restrict__ hall,       // [B][T][H] bf16 (exchange+output)
    unsigned* __restrict__ bar)              // flags[256] (zeroed)
{
    __shared__ unsigned short Wlds[64 * 1024];  // 128 KiB weight slab
    __shared__ float Gs[64 * 68];               // 17408 B gates
    __shared__ unsigned short Hs[64 * 16];      // 2 KiB h-patch gather

    const int tid = threadIdx.x;
    const int lane = tid & 63, wave = tid >> 6;
    const int quad = lane >> 4, l16 = lane & 15;
    const int wm = wave >> 2, wn = wave & 3;

    // XCD-aware persistent mapping: 8 n-tiles x 4 m-tiles per XCD
    const int id = blockIdx.x;
    const int xcd = id & 7, slot = id >> 3;   // slot 0..31
    const int nt = slot >> 2, mt = slot & 3;
    const int n0 = (xcd * 8 + nt) * 64;
    const int m0 = mt * 64;

    // barrier addressing: group = mt (the 64 blocks producing rows m0..m0+63)
    unsigned* myflag = bar + mt * 64 + xcd * 8 + nt;
    const unsigned* gflags = bar + mt * 64;

    // ---- one-time: stage Whh slab rows [n0, n0+64) into LDS (swizzled) ----
    for (int i = 0; i < 16; i++) {
        int q = i * 512 + tid;                // 8192 16B-chunks
        int row = q >> 7, kc = q & 127;       // 128 chunks per row
        int e = kc * 8;
        int de = row * 1024 + (e ^ ((row & 7) << 3));
        *(u32x4*)(Wlds + de) = *(const u32x4*)(WhhR + (long)(n0 + row) * H_ + e);
    }

    // Wih fragments in registers (16 n-rows x 256 k per wave = 32 VGPRs)
    const int nw = n0 + wn * 16 + l16;        // this lane's weight/gate col
    bf16x8 bwx[8];
    {
        const unsigned short* px = WihR + (long)nw * I_ + quad * 8;
#pragma unroll
        for (int kk = 0; kk < 8; kk++) bwx[kk] = *(const bf16x8*)(px + kk * 32);
    }
    const float bj = biasR[nw];

    // B ds_read base for this lane
    const unsigned short* bbase = Wlds + (wn * 16 + l16) * 1024;
    const int swz = (l16 & 7) << 3;

    // A row indices (2 m-fragments of 16 rows each)
    int arow[2];
    const unsigned short* xrow[2];
#pragma unroll
    for (int i = 0; i < 2; i++) {
        arow[i] = m0 + wm * 32 + i * 16 + l16;
        xrow[i] = xs + (long)arow[i] * T_ * I_ + quad * 8;
    }

    // register-resident c: thread handles items p = j*512 + tid
    float c_reg[2] = {0.f, 0.f};

    __syncthreads();  // Wlds staged

#pragma unroll 1
    for (int t = 0; t < T_; t++) {
        const f32x4 z = {0.f, 0.f, 0.f, 0.f};
        f32x4 acc[2] = {z, z};

        // phase 1: x_t @ Wih^T (K = 256) — independent of h; overlaps barrier
        {
            bf16x8 a[8][2];
#pragma unroll
            for (int kk = 0; kk < 8; kk++)
#pragma unroll
                for (int i = 0; i < 2; i++)
                    a[kk][i] = *(const bf16x8*)(xrow[i] + (long)t * I_ + kk * 32);
#pragma unroll
            for (int kk = 0; kk < 8; kk++)
#pragma unroll
                for (int i = 0; i < 2; i++)
                    acc[i] = MFMA16(a[kk][i], bwx[kk], acc[i]);
        }

        // wait: all 64 same-mt blocks published h_{t-1} (flag >= t)
        if (t > 0) {
            if (tid < 64) {
                int spins = 0;
                while (ldg_flag(gflags + tid) < (unsigned)t &&
                       spins < (1 << 20)) {
                    __builtin_amdgcn_s_sleep(1);
                    ++spins;
                }
            }
            __syncthreads();
        }

        // h_{t-1} source: step-rotated hall row (normal cached loads) or h0
        const unsigned short* hb;
        long hstr;
        if (t == 0) { hb = h0b;                      hstr = H_; }
        else        { hb = hall + (long)(t - 1) * H_; hstr = (long)T_ * H_; }
        const unsigned short* rp0 = hb + (long)arow[0] * hstr + quad * 8;
        const unsigned short* rp1 = hb + (long)arow[1] * hstr + quad * 8;

        // phase 2: h_prev @ Whh^T (K = 1024) — 8 sub-chunks, 2-deep pipeline
        {
            bf16x8 aa[2][4][2];   // [buf][kk][i], static-indexed via unroll
#pragma unroll
            for (int kk = 0; kk < 4; kk++) {
                aa[0][kk][0] = *(const bf16x8*)(rp0 + kk * 32);
                aa[0][kk][1] = *(const bf16x8*)(rp1 + kk * 32);
            }
#pragma unroll
            for (int sc = 0; sc < 8; sc++) {
                const int cur = sc & 1, nxt = cur ^ 1;
                if (sc < 7) {
                    const int kb = (sc + 1) * 4;
#pragma unroll
                    for (int kk = 0; kk < 4; kk++) {
                        aa[nxt][kk][0] = *(const bf16x8*)(rp0 + (kb + kk) * 32);
                        aa[nxt][kk][1] = *(const bf16x8*)(rp1 + (kb + kk) * 32);
                    }
                }
#pragma unroll
                for (int kk = 0; kk < 4; kk++) {
                    int e = ((sc * 4 + kk) * 32 + quad * 8) ^ swz;
                    bf16x8 bb = *(const bf16x8*)(bbase + e);
                    acc[0] = MFMA16(aa[cur][kk][0], bb, acc[0]);
                    acc[1] = MFMA16(aa[cur][kk][1], bb, acc[1]);
                }
            }
        }

        // gates + bias -> LDS (row = wm*32 + i*16 + quad*4 + r, col = wn*16+l16)
#pragma unroll
        for (int i = 0; i < 2; i++)
#pragma unroll
            for (int r = 0; r < 4; r++)
                Gs[(wm * 32 + i * 16 + quad * 4 + r) * 68 + wn * 16 + l16] =
                    acc[i][r] + bj;
        __syncthreads();

        // fused cell: 64 rows x 16 units; c register-resident; h -> Hs
#pragma unroll
        for (int j = 0; j < 2; j++) {
            int p = j * 512 + tid;
            int row = p >> 4, u = p & 15;
            float gi = Gs[row * 68 + u * 4 + 0];
            float gf = Gs[row * 68 + u * 4 + 1];
            float gg = Gs[row * 68 + u * 4 + 2];
            float go = Gs[row * 68 + u * 4 + 3];
            float ii = sigm(gi), ff = sigm(gf), g3 = tanhf(gg), oo = sigm(go);
            float cn = ff * c_reg[j] + ii * g3;
            float hh = oo * tanhf(cn);
            c_reg[j] = cn;
            Hs[row * 16 + u] = f2bf(hh);
        }
        __syncthreads();

        // h patch -> hall[b][t][:] as 128 x 16B memside write-through stores
        if (tid < 128) {
            int row = tid >> 1, half = tid & 1;
            u32x4 v = *(const u32x4*)(Hs + row * 16 + half * 8);
            unsigned short* dst = hall +
                ((long)(m0 + row) * T_ + t) * H_ + (n0 >> 2) + half * 8;
            stg_sys128(dst, v);
        }

        // arrive: h stores acked at coherence point, then set own flag
        if (t < T_ - 1) {
            asm volatile("s_waitcnt vmcnt(0)" ::: "memory");
            __syncthreads();   // all waves drained; also protects Gs/Hs
            if (tid == 0) stg_flag(myflag, (unsigned)(t + 1));
        }
    }
}

// ---------------------------------------------------------------------------
// scores: per-b S = hall[b](32x1024) @ encB[b]^T (128x1024)^T, fused softmax.
// ---------------------------------------------------------------------------
__global__ __launch_bounds__(256) void scores_kernel(
    const unsigned short* __restrict__ hall, // [B][T][H]
    const unsigned short* __restrict__ encB, // [B][S][H]
    float* __restrict__ probs,               // [B][T][S]
    unsigned short* __restrict__ PB)         // [B][T][S] bf16
{
    __shared__ float Sc[32 * 132];

    const int tid = threadIdx.x;
    const int lane = tid & 63, wave = tid >> 6;
    const int quad = lane >> 4, l16 = lane & 15;
    const int b = blockIdx.x;
    const int nw = wave;  // 4 waves x 32 s-cols

    const unsigned short* pa0 = hall + ((long)b * T_ + l16) * H_ + quad * 8;
    const unsigned short* pa1 = hall + ((long)b * T_ + 16 + l16) * H_ + quad * 8;
    const unsigned short* pb0 = encB + ((long)b * S_ + nw * 32 + l16) * H_ + quad * 8;
    const unsigned short* pb1 = pb0 + 16 * H_;

    const f32x4 z = {0.f, 0.f, 0.f, 0.f};
    f32x4 acc00 = z, acc01 = z, acc10 = z, acc11 = z;

#pragma unroll 4
    for (int k0 = 0; k0 < H_; k0 += 32) {
        bf16x8 a0 = *(const bf16x8*)(pa0 + k0);
        bf16x8 a1 = *(const bf16x8*)(pa1 + k0);
        bf16x8 b0 = *(const bf16x8*)(pb0 + k0);
        bf16x8 b1 = *(const bf16x8*)(pb1 + k0);
        acc00 = MFMA16(a0, b0, acc00);
        acc01 = MFMA16(a0, b1, acc01);
        acc10 = MFMA16(a1, b0, acc10);
        acc11 = MFMA16(a1, b1, acc11);
    }
#pragma unroll
    for (int r = 0; r < 4; r++) {
        int row0 = quad * 4 + r;
        int col0 = nw * 32 + l16;
        Sc[row0 * 132 + col0]            = acc00[r];
        Sc[row0 * 132 + col0 + 16]       = acc01[r];
        Sc[(row0 + 16) * 132 + col0]      = acc10[r];
        Sc[(row0 + 16) * 132 + col0 + 16] = acc11[r];
    }
    __syncthreads();
    // softmax: wave handles 8 rows; 128 cols = 2 per lane
    for (int r = 0; r < 8; r++) {
        int row = wave * 8 + r;
        float v0 = Sc[row * 132 + lane];
        float v1 = Sc[row * 132 + 64 + lane];
        float mx = fmaxf(v0, v1);
#pragma unroll
        for (int off = 32; off > 0; off >>= 1) mx = fmaxf(mx, __shfl_xor(mx, off));
        float e0 = __expf(v0 - mx), e1 = __expf(v1 - mx);
        float s = e0 + e1;
#pragma unroll
        for (int off = 32; off > 0; off >>= 1) s += __shfl_xor(s, off);
        float inv = 1.0f / s;
        float p0 = e0 * inv, p1 = e1 * inv;
        long o = ((long)b * T_ + row) * S_;
        probs[o + lane] = p0;
        probs[o + 64 + lane] = p1;
        PB[o + lane] = f2bf(p0);
        PB[o + 64 + lane] = f2bf(p1);
    }
}

// ---------------------------------------------------------------------------
// ctx: C[b] = P[b](32x128) @ encB[b](128x1024) -> CTX bf16. grid(B, 4).
// ---------------------------------------------------------------------------
__global__ __launch_bounds__(256) void ctx_kernel(
    const unsigned short* __restrict__ encB, // [B][S][H]
    const unsigned short* __restrict__ PB,   // [B][T][S]
    unsigned short* __restrict__ ctxo)       // [B*T][H] bf16
{
    __shared__ unsigned short Es[S_ * 256];  // 64 KB

    const int tid = threadIdx.x;
    const int lane = tid & 63, wave = tid >> 6;
    const int quad = lane >> 4, l16 = lane & 15;
    const int b = blockIdx.x;
    const int h0 = blockIdx.y * 256;

    // stage encB[b][:, h0:h0+256] -> LDS [s][256]
    for (int i = tid; i < S_ * 32; i += 256) {
        int s = i >> 5, hc = (i & 31) * 8;
        *(u32x4*)(Es + s * 256 + hc) =
            *(const u32x4*)(encB + ((long)b * S_ + s) * H_ + h0 + hc);
    }
    // A fragments (P rows t, k = s), direct loads
    bf16x8 a[2][4];
#pragma unroll
    for (int i = 0; i < 2; i++)
#pragma unroll
        for (int ks = 0; ks < 4; ks++)
            a[i][ks] = *(const bf16x8*)(PB + ((long)b * T_ + i * 16 + l16) * S_ +
                                        ks * 32 + quad * 8);
    __syncthreads();

    f32x4 acc[2][4];
    const f32x4 z = {0.f, 0.f, 0.f, 0.f};
#pragma unroll
    for (int i = 0; i < 2; i++)
#pragma unroll
        for (int j = 0; j < 4; j++) acc[i][j] = z;

    const int cw = wave * 64;
#pragma unroll
    for (int ks = 0; ks < 4; ks++) {
        const int kb = ks * 32 + quad * 8;
#pragma unroll
        for (int j = 0; j < 4; j++) {
            const int col = cw + j * 16 + l16;
            bf16x8 bb;
#pragma unroll
            for (int e = 0; e < 8; e++) bb[e] = (short)Es[(kb + e) * 256 + col];
            acc[0][j] = MFMA16(a[0][ks], bb, acc[0][j]);
            acc[1][j] = MFMA16(a[1][ks], bb, acc[1][j]);
        }
    }
#pragma unroll
    for (int i = 0; i < 2; i++)
#pragma unroll
        for (int j = 0; j < 4; j++)
#pragma unroll
            for (int r = 0; r < 4; r++) {
                int row = i * 16 + quad * 4 + r;
                int col = h0 + cw + j * 16 + l16;
                ctxo[((long)b * T_ + row) * H_ + col] = f2bf(acc[i][j][r]);
            }
}

// ---------------------------------------------------------------------------
// fc: out = [ctx | h](8192x2048) @ WfcR^T (256x2048) + bfc. Tile 64x128.
// ---------------------------------------------------------------------------
__global__ __launch_bounds__(256) void fc_kernel(
    const unsigned short* __restrict__ ctxo, // [B*T][H]
    const unsigned short* __restrict__ hall, // [B*T][H]
    const unsigned short* __restrict__ WfcR,
    const float* __restrict__ bfc,
    float* __restrict__ out)
{
    __shared__ __align__(16) unsigned short As[64 * 40];
    __shared__ __align__(16) unsigned short Bs[128 * 40];

    const int tid = threadIdx.x;
    const int lane = tid & 63, wave = tid >> 6;
    const int wm = wave >> 1, wn = wave & 1;
    const int quad = lane >> 4, l16 = lane & 15;
    const int n0 = blockIdx.x * 128, m0 = blockIdx.y * 64;

    const int arow = tid >> 2, akc = (tid & 3) * 8;
    const int brow = tid >> 1, bkc = (tid & 1) * 16;

    f32x4 acc[2][4];
    const f32x4 z = {0.f, 0.f, 0.f, 0.f};
#pragma unroll
    for (int i = 0; i < 2; i++)
#pragma unroll
        for (int j = 0; j < 4; j++) acc[i][j] = z;

    for (int k0 = 0; k0 < K2; k0 += 32) {
        const unsigned short* asrc = (k0 < H_)
            ? ctxo + (long)(m0 + arow) * H_ + k0 + akc
            : hall + (long)(m0 + arow) * H_ + (k0 - H_) + akc;
        *(u32x4*)(As + arow * 40 + akc) = *(const u32x4*)asrc;
        const unsigned short* src = WfcR + (long)(n0 + brow) * K2 + k0 + bkc;
        *(u32x4*)(Bs + brow * 40 + bkc)     = *(const u32x4*)src;
        *(u32x4*)(Bs + brow * 40 + bkc + 8) = *(const u32x4*)(src + 8);
        __syncthreads();
        bf16x8 a0 = *(const bf16x8*)(As + (wm * 32 + l16) * 40 + quad * 8);
        bf16x8 a1 = *(const bf16x8*)(As + (wm * 32 + 16 + l16) * 40 + quad * 8);
#pragma unroll
        for (int j = 0; j < 4; j++) {
            bf16x8 bb = *(const bf16x8*)(Bs + (wn * 64 + j * 16 + l16) * 40 + quad * 8);
            acc[0][j] = MFMA16(a0, bb, acc[0][j]);
            acc[1][j] = MFMA16(a1, bb, acc[1][j]);
        }
        __syncthreads();
    }
#pragma unroll
    for (int i = 0; i < 2; i++)
#pragma unroll
        for (int j = 0; j < 4; j++)
#pragma unroll
            for (int r = 0; r < 4; r++) {
                int row = m0 + wm * 32 + i * 16 + quad * 4 + r;
                int col = n0 + wn * 64 + j * 16 + l16;
                out[(long)row * O_ + col] = acc[i][j][r] + bfc[col];
            }
}

// ---------------------------------------------------------------------------
extern "C" void kernel_launch(void* const* d_in, const int* in_sizes, int n_in,
                              void* d_out, int out_size, void* d_ws, size_t ws_size,
                              hipStream_t stream) {
    const float* x   = (const float*)d_in[0];
    const float* enc = (const float*)d_in[1];
    const float* Wih = (const float*)d_in[2];
    const float* Whh = (const float*)d_in[3];
    const float* bih = (const float*)d_in[4];
    const float* bhh = (const float*)d_in[5];
    const float* Wfc = (const float*)d_in[6];
    const float* bfc = (const float*)d_in[7];
    float* out = (float*)d_out;

    char* ws = (char*)d_ws;
    // workspace layout (bytes); total ~120.6 MB
    unsigned short* WIHR = (unsigned short*)(ws + 0);           //  2,097,152
    unsigned short* WHHR = (unsigned short*)(ws + 2097152);     //  8,388,608
    unsigned short* WFCR = (unsigned short*)(ws + 10485760);    //  1,048,576
    float*          BIAS = (float*)         (ws + 11534336);    //     16,384
    unsigned short* XS   = (unsigned short*)(ws + 11550720);    //  4,194,304
    unsigned short* H0   = (unsigned short*)(ws + 15745024);    //    524,288
    unsigned*       BAR  = (unsigned*)      (ws + 16793600);    // flags[256]
    unsigned short* HALL = (unsigned short*)(ws + 17842176);    // 16,777,216
    unsigned short* ENCB = (unsigned short*)(ws + 34619392);    // 67,108,864
    unsigned short* PB   = (unsigned short*)(ws + 101728256);   //  2,097,152
    unsigned short* CTX  = (unsigned short*)(ws + 103825408);   // 16,777,216

    prep_kernel<<<8192, 256, 0, stream>>>(x, enc, Wih, Whh, bih, bhh, Wfc,
                                          WIHR, WHHR, WFCR, BIAS, XS, ENCB,
                                          H0, BAR);

    // all 32 LSTM steps in one persistent cooperative launch (512 threads)
    {
        void* args[] = {(void*)&XS, (void*)&WIHR, (void*)&WHHR, (void*)&BIAS,
                        (void*)&H0, (void*)&HALL, (void*)&BAR};
        (void)hipLaunchCooperativeKernel(reinterpret_cast<void*>(steps_kernel),
                                         dim3(256), dim3(512), args, 0, stream);
    }

    scores_kernel<<<B_, 256, 0, stream>>>(HALL, ENCB,
                                          out + (long)B_ * T_ * O_, PB);
    ctx_kernel<<<dim3(B_, 4), 256, 0, stream>>>(ENCB, PB, CTX);
    fc_kernel<<<dim3(2, 128), 256, 0, stream>>>(CTX, HALL, WFCR, bfc, out);
}